// Round 8
// baseline (177.667 us; speedup 1.0000x reference)
//
#include <hip/hip_runtime.h>

#define SIG0 0.17f
#define SIG1 4.86f

__device__ __constant__ float c_filt0[25] = {
  0.04f,0.04f,0.05f,0.04f,0.04f,
  0.04f,0.03f,0.04f,0.03f,0.04f,
  0.05f,0.04f,0.05f,0.04f,0.05f,
  0.04f,0.03f,0.04f,0.03f,0.04f,
  0.04f,0.04f,0.05f,0.04f,0.04f};
__device__ __constant__ float c_f1d[5] = {0.05f,0.25f,0.4f,0.25f,0.05f};

static __device__ __forceinline__ int iclamp(int v, int lo, int hi){
  return v < lo ? lo : (v > hi ? hi : v);
}

// Padded level buffers: level size S stored as (S+4) rows x (S+8) cols,
// logical (y,x) at [(y+2)*(S+8) + (x+4)], apron = replicate of border.
// g1: S=256 PS=264 (img stride 68640); g2: S=128 PS=136 (17952); g3: S=64 PS=72 (4896)

struct FS {                      // fused kernel: 64x16 output tile
  float sg[2][20][76];           // lap tile rows y0-2..y0+17, cols x0-4..x0+67 (72 used)
  float s1[2][12][44];           // g_{k+1} tile rows y0/2-2.., cols x0/2-4.. (40 used)
  float red[4];
};
struct DS {                      // down kernel: 64x8 output tile
  float st[20][136];
  float hs[20][64];
};
struct TS {                      // tail kernel
  float A3[2][64][66];
  float A4[2][32][34];
  float A5[2][16][18];
  float A6[2][8][10];
  float red[4];
};

// ================= down body: padded in -> padded out (out tile 64x8) =================
__device__ __forceinline__ void down_body(const float* __restrict__ in0, float* __restrict__ out0,
                                          int PSI, int PSO, int Sout, int xo0, int yo0, char* smem){
  DS* S = (DS*)smem;
  int tid = threadIdx.x;
  for (int f=tid; f<20*34; f+=256){
    int r=f/34, c4=f-34*r;
    *(float4*)&S->st[r][4*c4] = *(const float4*)&in0[(size_t)(2*yo0+r)*PSI + 2*xo0 + 4*c4];
  }
  __syncthreads();
  for (int f=tid; f<20*64; f+=256){
    int r=f>>6, xo=f&63;
    const float* rp = &S->st[r][2*xo+2];
    S->hs[r][xo] = 0.05f*rp[0]+0.25f*rp[1]+0.4f*rp[2]+0.25f*rp[3]+0.05f*rp[4];
  }
  __syncthreads();
  for (int f=tid; f<8*64; f+=256){
    int yo=f>>6, xo=f&63;
    int Y=yo0+yo, X=xo0+xo;
    float v = 0.05f*S->hs[2*yo][xo]+0.25f*S->hs[2*yo+1][xo]+0.4f*S->hs[2*yo+2][xo]
            +0.25f*S->hs[2*yo+3][xo]+0.05f*S->hs[2*yo+4][xo];
    int rlo=(Y==0)?0:(Y+2), rhi=(Y==Sout-1)?(Sout+3):(Y+2);
    int clo=(X==0)?0:(X+4), chi=(X==Sout-1)?(Sout+7):(X+4);
    for (int rr=rlo; rr<=rhi; rr++)
      for (int cc=clo; cc<=chi; cc++)
        out0[(size_t)rr*PSO+cc] = v;
  }
}

// ================= k_d1: gamma + down0 (raw input -> padded g1), out tile 64x8 =================
__global__ __launch_bounds__(256)
void k_d1(const float* __restrict__ hin, const float* __restrict__ lin,
          float* __restrict__ g1){
  __shared__ DS S;
  int xo0 = blockIdx.x*64, yo0 = blockIdx.y*8, z = blockIdx.z;
  const float* in = (z<16)? hin + (size_t)z*262144 : lin + (size_t)(z-16)*262144;
  float* out0 = g1 + (size_t)z*68640;
  int tid = threadIdx.x;
  const float e = 0.3846153846153846f;
  for (int f=tid; f<20*34; f+=256){
    int r=f/34, c4=f-34*r;
    int yy = iclamp(2*yo0-2+r, 0, 511);
    int xb = 2*xo0-4+4*c4;
    const float* rp = in + (size_t)yy*512;
    float4 v;
    if (xb>=0 && xb<=508) v = *(const float4*)&rp[xb];
    else { v.x=rp[iclamp(xb,0,511)]; v.y=rp[iclamp(xb+1,0,511)];
           v.z=rp[iclamp(xb+2,0,511)]; v.w=rp[iclamp(xb+3,0,511)]; }
    v.x=__powf(v.x,e); v.y=__powf(v.y,e); v.z=__powf(v.z,e); v.w=__powf(v.w,e);
    *(float4*)&S.st[r][4*c4] = v;
  }
  __syncthreads();
  for (int f=tid; f<20*64; f+=256){
    int r=f>>6, xo=f&63;
    const float* rp = &S.st[r][2*xo+2];
    S.hs[r][xo] = 0.05f*rp[0]+0.25f*rp[1]+0.4f*rp[2]+0.25f*rp[3]+0.05f*rp[4];
  }
  __syncthreads();
  for (int f=tid; f<8*64; f+=256){
    int yo=f>>6, xo=f&63;
    int Y=yo0+yo, X=xo0+xo;
    float v = 0.05f*S.hs[2*yo][xo]+0.25f*S.hs[2*yo+1][xo]+0.4f*S.hs[2*yo+2][xo]
            +0.25f*S.hs[2*yo+3][xo]+0.05f*S.hs[2*yo+4][xo];
    int rlo=(Y==0)?0:(Y+2), rhi=(Y==255)?259:(Y+2);
    int clo=(X==0)?0:(X+4), chi=(X==255)?263:(X+4);
    for (int rr=rlo; rr<=rhi; rr++)
      for (int cc=clo; cc<=chi; cc++)
        out0[(size_t)rr*264+cc] = v;
  }
}

// ================= fused body: lap + replicate-fix + den + diff + reduce =================
// GAMMA=1: a0/a1 are raw 512x512 inputs (apply powf); GAMMA=0: padded g_k buffers (stride PS0).
template<int GAMMA>
__device__ __forceinline__ void fused_body(FS* S,
    const float* __restrict__ a0, const float* __restrict__ a1, int PS0,
    const float* __restrict__ s10, const float* __restrict__ s11, int PS1,
    int Simg, int x0, int y0, int lev, int b, float* __restrict__ accum){
  int t = threadIdx.x;
  const float e = 0.3846153846153846f;

  // ---- p1a: stage sg (240 segments of 12 floats; one div) ----
  if (t < 240){
    int img = t >= 120; int t2 = img ? t-120 : t;
    int r = t2/6, q3 = t2 - 6*r;
    float w[12];
    if (GAMMA){
      int yy = iclamp(y0-2+r, 0, 511);
      int xb = x0-4+12*q3;
      const float* rp = (img ? a1 : a0) + (size_t)yy*512;
      if (xb >= 0 && xb <= 500){
        *(float4*)&w[0] = *(const float4*)&rp[xb];
        *(float4*)&w[4] = *(const float4*)&rp[xb+4];
        *(float4*)&w[8] = *(const float4*)&rp[xb+8];
      } else {
        #pragma unroll
        for (int j=0;j<12;j++) w[j] = rp[iclamp(xb+j,0,511)];
      }
      #pragma unroll
      for (int j=0;j<12;j++) w[j] = __powf(w[j], e);
    } else {
      const float* rp = (img ? a1 : a0) + (size_t)(y0+r)*PS0 + x0 + 12*q3;
      *(float4*)&w[0] = *(const float4*)&rp[0];
      *(float4*)&w[4] = *(const float4*)&rp[4];
      *(float4*)&w[8] = *(const float4*)&rp[8];
    }
    float* dp = &S->sg[img][r][12*q3];
    *(float4*)&dp[0] = *(float4*)&w[0];
    *(float4*)&dp[4] = *(float4*)&w[4];
    *(float4*)&dp[8] = *(float4*)&w[8];
  }
  // ---- p1b: stage s1 (240 f4 segments: 2 img x 12 rows x 10 f4 = 40 cols) ----
  if (t < 240){
    int img = t >= 120; int t2 = img ? t-120 : t;
    int ro = t2/10, co = t2 - 10*ro;
    const float* src = (img ? s11 : s10) + (size_t)(y0/2+ro)*PS1 + x0/2 + 4*co;
    *(float4*)&S->s1[img][ro][4*co] = *(const float4*)src;
  }
  __syncthreads();

  // ---- p2: lap in place; waves 0-1 even rows, waves 2-3 odd rows (wave-uniform branch) ----
  {
    int tt = t & 127;
    bool ew = t < 128;
    if (tt < 120){
      int img = tt >= 60; int t2 = img ? tt-60 : tt;
      int rh = t2/6, q3 = t2 - 6*rh;       // rh 0..9
      int r = ew ? 2*rh : 2*rh+1;
      int cb = 6*q3;
      float B[12], C[12], u[12];
      {
        const float* pB = &S->s1[img][rh+1][cb];
        const float* pC = &S->s1[img][rh+2][cb];
        *(float4*)&B[0]=*(const float4*)&pB[0]; *(float4*)&B[4]=*(const float4*)&pB[4]; *(float4*)&B[8]=*(const float4*)&pB[8];
        *(float4*)&C[0]=*(const float4*)&pC[0]; *(float4*)&C[4]=*(const float4*)&pC[4]; *(float4*)&C[8]=*(const float4*)&pC[8];
      }
      if (ew){
        float A[12];
        const float* pA = &S->s1[img][rh][cb];
        *(float4*)&A[0]=*(const float4*)&pA[0]; *(float4*)&A[4]=*(const float4*)&pA[4]; *(float4*)&A[8]=*(const float4*)&pA[8];
        #pragma unroll
        for (int m=0;m<6;m++){
          float hEA = 0.05f*A[m+1]+0.4f*A[m+2]+0.05f*A[m+3];
          float hEB = 0.05f*B[m+1]+0.4f*B[m+2]+0.05f*B[m+3];
          float hEC = 0.05f*C[m+1]+0.4f*C[m+2]+0.05f*C[m+3];
          u[2*m]   = 0.2f*hEA + 1.6f*hEB + 0.2f*hEC;
          float hOA = 0.25f*(A[m+2]+A[m+3]);
          float hOB = 0.25f*(B[m+2]+B[m+3]);
          float hOC = 0.25f*(C[m+2]+C[m+3]);
          u[2*m+1] = 0.2f*hOA + 1.6f*hOB + 0.2f*hOC;
        }
      } else {
        #pragma unroll
        for (int m=0;m<6;m++){
          float hEB = 0.05f*B[m+1]+0.4f*B[m+2]+0.05f*B[m+3];
          float hEC = 0.05f*C[m+1]+0.4f*C[m+2]+0.05f*C[m+3];
          u[2*m]   = hEB + hEC;
          u[2*m+1] = 0.25f*(B[m+2]+B[m+3]) + 0.25f*(C[m+2]+C[m+3]);
        }
      }
      float* dp = &S->sg[img][r][12*q3];
      float v[12];
      *(float4*)&v[0]=*(float4*)&dp[0]; *(float4*)&v[4]=*(float4*)&dp[4]; *(float4*)&v[8]=*(float4*)&dp[8];
      #pragma unroll
      for (int j=0;j<12;j++) v[j] -= u[j];
      *(float4*)&dp[0]=*(float4*)&v[0]; *(float4*)&dp[4]=*(float4*)&v[4]; *(float4*)&dp[8]=*(float4*)&v[8];
    }
  }
  __syncthreads();

  // ---- replicate fix-up on lap tile borders ----
  bool top=(y0==0), bot=(y0+16==Simg), lft=(x0==0), rgt=(x0+64==Simg);
  if (top|bot|lft|rgt){
    for (int f=t; f<2*18; f+=256){
      int img = f>=18; int q = img ? f-18 : f;
      if (top){ float4 v=*(float4*)&S->sg[img][2][4*q];
                *(float4*)&S->sg[img][0][4*q]=v; *(float4*)&S->sg[img][1][4*q]=v; }
      if (bot){ float4 v=*(float4*)&S->sg[img][17][4*q];
                *(float4*)&S->sg[img][18][4*q]=v; *(float4*)&S->sg[img][19][4*q]=v; }
    }
    __syncthreads();
    for (int f=t; f<2*20; f+=256){
      int img = f>=20; int r = img ? f-20 : f;
      if (lft){ float v=S->sg[img][r][4];  float4 vv={v,v,v,v}; *(float4*)&S->sg[img][r][0]=vv; }
      if (rgt){ float v=S->sg[img][r][67]; float4 vv={v,v,v,v}; *(float4*)&S->sg[img][r][68]=vv; }
    }
    __syncthreads();
  }

  // ---- p3: streaming den conv (box trick). Thread: 4x2 quad of ONE image (img = t&1). ----
  // den = SIG0 + 0.04*T + 0.01*s05 - 0.01*s03
  float vacc = 0.f;
  {
    int img = t & 1, quad = t >> 1;
    int qx = quad & 15, qy = quad >> 4;   // qx 0..15, qy 0..7
    int cb = 4*qx, rb = 2*qy;
    float T0[4]={0,0,0,0}, T1[4]={0,0,0,0};
    float s5a[4], s5b[4], s3a[4], s3b[4], n0[4], n1[4];
    #pragma unroll
    for (int r=0;r<6;r++){
      float w[12];
      const float* rp = &S->sg[img][rb+r][cb];
      *(float4*)&w[0]=*(const float4*)&rp[0];
      *(float4*)&w[4]=*(const float4*)&rp[4];
      *(float4*)&w[8]=*(const float4*)&rp[8];
      float aw[8];
      #pragma unroll
      for (int j=0;j<8;j++) aw[j] = fabsf(w[j+2]);
      float h0 = ((aw[0]+aw[1])+(aw[2]+aw[3]))+aw[4];
      float h1 = h0 - aw[0] + aw[5];
      float h2 = h1 - aw[1] + aw[6];
      float h3 = h2 - aw[2] + aw[7];
      float hh[4] = {h0,h1,h2,h3};
      if (r<=4){
        #pragma unroll
        for (int c=0;c<4;c++) T0[c] += hh[c];
      }
      if (r>=1){
        #pragma unroll
        for (int c=0;c<4;c++) T1[c] += hh[c];
      }
      if (r==0){
        for (int c=0;c<4;c++) s5a[c] = aw[c+2];
      }
      if (r==1){
        for (int c=0;c<4;c++){ s3a[c] = aw[c+1]+aw[c+3]; s5b[c] = aw[c+2]; }
      }
      if (r==2){
        for (int c=0;c<4;c++){ s5a[c] += aw[c]+aw[c+2]+aw[c+4]; n0[c]=w[c+4]; s3b[c] = aw[c+1]+aw[c+3]; }
      }
      if (r==3){
        for (int c=0;c<4;c++){ s3a[c] += aw[c+1]+aw[c+3]; s5b[c] += aw[c]+aw[c+2]+aw[c+4]; n1[c]=w[c+4]; }
      }
      if (r==4){
        for (int c=0;c<4;c++){ s5a[c] += aw[c+2]; s3b[c] += aw[c+1]+aw[c+3]; }
      }
      if (r==5){
        for (int c=0;c<4;c++) s5b[c] += aw[c+2];
      }
    }
    float qv[8];
    #pragma unroll
    for (int c=0;c<4;c++){
      float d0 = SIG0 + 0.04f*T0[c] + 0.01f*s5a[c] - 0.01f*s3a[c];
      float d1 = SIG0 + 0.04f*T1[c] + 0.01f*s5b[c] - 0.01f*s3b[c];
      qv[c]   = __fdividef(n0[c], d0);
      qv[4+c] = __fdividef(n1[c], d1);
    }
    #pragma unroll
    for (int i=0;i<8;i++){
      float o = __shfl_xor(qv[i], 1);
      float d = qv[i] - o;
      vacc += d*d;
    }
    if (img) vacc = 0.f;   // count each pair once
  }
  #pragma unroll
  for (int off=32; off>0; off>>=1) vacc += __shfl_down(vacc, off);
  if ((t&63)==0) S->red[t>>6] = vacc;
  __syncthreads();
  if (t==0)
    atomicAdd(&accum[lev*16+b], S->red[0]+S->red[1]+S->red[2]+S->red[3]);
}

// ================= tail (levels 3..6) helpers =================
static __device__ __forceinline__ void down_lds(const float* Ain, int ldi, int Sin,
                                                float* Aout, int ldo, int Sout,
                                                int tid, int NT){
  int tot = 2*Sout*Sout;
  for (int f=tid; f<tot; f+=NT){
    int img = f/(Sout*Sout), rem = f%(Sout*Sout), y=rem/Sout, x=rem%Sout;
    const float* A = Ain + img*Sin*ldi;
    float s=0.f;
    #pragma unroll
    for (int i=0;i<5;i++){
      int yy=iclamp(2*y+i-2,0,Sin-1);
      float rs=0.f;
      #pragma unroll
      for (int j=0;j<5;j++){
        int xx=iclamp(2*x+j-2,0,Sin-1);
        rs += c_f1d[j]*A[yy*ldi+xx];
      }
      s += c_f1d[i]*rs;
    }
    Aout[img*Sout*ldo + y*ldo + x] = s;
  }
}

static __device__ __forceinline__ void lap_lds(float* Ak, int ldk, int S,
                                               const float* Ag, int ldg,
                                               int tid, int NT){
  int Sg = S>>1;
  int tot = 2*S*S;
  for (int f=tid; f<tot; f+=NT){
    int img=f/(S*S), rem=f%(S*S), y=rem/S, x=rem%S;
    const float* G = Ag + img*Sg*ldg;
    int y2=y>>1, x2=x>>1;
    int ry0,ry1,ry2; float wy0,wy1,wy2;
    if (!(y&1)){ ry0=iclamp(y2-1,0,Sg-1); ry1=y2; ry2=iclamp(y2+1,0,Sg-1); wy0=0.2f; wy1=1.6f; wy2=0.2f; }
    else { ry0=y2; ry1=iclamp(y2+1,0,Sg-1); ry2=y2; wy0=1.f; wy1=1.f; wy2=0.f; }
    int cx0,cx1,cx2; float wx0,wx1,wx2;
    if (!(x&1)){ cx0=iclamp(x2-1,0,Sg-1); cx1=x2; cx2=iclamp(x2+1,0,Sg-1); wx0=0.05f; wx1=0.4f; wx2=0.05f; }
    else { cx0=x2; cx1=iclamp(x2+1,0,Sg-1); cx2=x2; wx0=0.25f; wx1=0.25f; wx2=0.f; }
    float u0 = wx0*G[ry0*ldg+cx0]+wx1*G[ry0*ldg+cx1]+wx2*G[ry0*ldg+cx2];
    float u1 = wx0*G[ry1*ldg+cx0]+wx1*G[ry1*ldg+cx1]+wx2*G[ry1*ldg+cx2];
    float u2 = wx0*G[ry2*ldg+cx0]+wx1*G[ry2*ldg+cx1]+wx2*G[ry2*ldg+cx2];
    Ak[img*S*ldk + y*ldk + x] -= wy0*u0+wy1*u1+wy2*u2;
  }
}

static __device__ __forceinline__ float diff_lds(const float* A, int ld, int S,
                                                 int tid, int NT){
  float v=0.f;
  const float* Ah = A;
  const float* Al = A + S*ld;
  for (int f=tid; f<S*S; f+=NT){
    int y=f/S, x=f%S;
    float dh=SIG0, dl=SIG0;
    #pragma unroll
    for (int i=0;i<5;i++){
      int yy=iclamp(y+i-2,0,S-1);
      #pragma unroll
      for (int j=0;j<5;j++){
        int xx=iclamp(x+j-2,0,S-1);
        float w=c_filt0[i*5+j];
        dh += w*fabsf(Ah[yy*ld+xx]);
        dl += w*fabsf(Al[yy*ld+xx]);
      }
    }
    float d = __fdividef(Ah[y*ld+x],dh) - __fdividef(Al[y*ld+x],dl);
    v += d*d;
  }
  return v;
}

__device__ void tail_body(const float* __restrict__ g3, float* __restrict__ accum,
                          int b, char* smem){
  TS* T = (TS*)smem;
  int tid = threadIdx.x;
  const float* s0  = g3 + (size_t)b*4896 + 148;        // (2,4) of padded 72-stride
  const float* s1p = g3 + (size_t)(b+16)*4896 + 148;
  for (int f=tid; f<2*4096; f+=256){
    int img=f>>12, rem=f&4095, r=rem>>6, c=rem&63;
    T->A3[img][r][c] = (img? s1p : s0)[(size_t)r*72+c];
  }
  __syncthreads();
  down_lds(&T->A3[0][0][0],66,64,&T->A4[0][0][0],34,32,tid,256);
  __syncthreads();
  down_lds(&T->A4[0][0][0],34,32,&T->A5[0][0][0],18,16,tid,256);
  __syncthreads();
  down_lds(&T->A5[0][0][0],18,16,&T->A6[0][0][0],10,8,tid,256);
  __syncthreads();
  lap_lds(&T->A3[0][0][0],66,64,&T->A4[0][0][0],34,tid,256);
  __syncthreads();
  float v3 = diff_lds(&T->A3[0][0][0],66,64,tid,256);
  lap_lds(&T->A4[0][0][0],34,32,&T->A5[0][0][0],18,tid,256);
  __syncthreads();
  float v4 = diff_lds(&T->A4[0][0][0],34,32,tid,256);
  lap_lds(&T->A5[0][0][0],18,16,&T->A6[0][0][0],10,tid,256);
  __syncthreads();
  float v5 = diff_lds(&T->A5[0][0][0],18,16,tid,256);
  float v6 = 0.f;
  for (int f=tid; f<64; f+=256){
    float ch = T->A6[0][f>>3][f&7];
    float cl = T->A6[1][f>>3][f&7];
    float d = __fdividef(ch, fabsf(ch)+SIG1) - __fdividef(cl, fabsf(cl)+SIG1);
    v6 += d*d;
  }
  float vs[4] = {v3, v4, v5, v6};
  #pragma unroll
  for (int k=0;k<4;k++){
    float v = vs[k];
    #pragma unroll
    for (int off=32; off>0; off>>=1) v += __shfl_down(v, off);
    if ((tid&63)==0) T->red[tid>>6] = v;
    __syncthreads();
    if (tid==0)
      accum[(3+k)*16 + b] = T->red[0]+T->red[1]+T->red[2]+T->red[3];
    __syncthreads();
  }
}

// ================= co-launched dispatch kernels =================
__global__ __launch_bounds__(256)
void k_d2(const float* __restrict__ h, const float* __restrict__ l,
          const float* __restrict__ g1, float* __restrict__ g2,
          float* __restrict__ accum){
  extern __shared__ char smem[];
  if (blockIdx.z < 16){
    int b = blockIdx.z, x0 = blockIdx.x*64, y0 = blockIdx.y*16;
    fused_body<1>((FS*)smem, h+(size_t)b*262144, l+(size_t)b*262144, 0,
                  g1+(size_t)b*68640, g1+(size_t)(b+16)*68640, 264,
                  512, x0, y0, 0, b, accum);
  } else {
    int id = (blockIdx.z-16)*256 + blockIdx.y*8 + blockIdx.x;
    int img = id>>5, rem = id&31, xt = rem&1, yt = rem>>1;
    down_body(g1+(size_t)img*68640, g2+(size_t)img*17952, 264, 136, 128, xt*64, yt*8, smem);
  }
}

__global__ __launch_bounds__(256)
void k_d4(const float* __restrict__ g1, float* __restrict__ g2,
          float* __restrict__ g3, float* __restrict__ accum){
  extern __shared__ char smem[];
  if (blockIdx.z < 16){
    int b = blockIdx.z, x0 = blockIdx.x*64, y0 = blockIdx.y*16;
    fused_body<0>((FS*)smem, g1+(size_t)b*68640, g1+(size_t)(b+16)*68640, 264,
                  g2+(size_t)b*17952, g2+(size_t)(b+16)*17952, 136,
                  256, x0, y0, 1, b, accum);
  } else {
    int id = (blockIdx.z-16)*64 + blockIdx.y*4 + blockIdx.x;
    int img = id>>3, yt = id&7;
    down_body(g2+(size_t)img*17952, g3+(size_t)img*4896, 136, 72, 64, 0, yt*8, smem);
  }
}

__global__ __launch_bounds__(256)
void k_d5(const float* __restrict__ g2, const float* __restrict__ g3,
          float* __restrict__ accum){
  extern __shared__ char smem[];
  if (blockIdx.z < 16){
    int b = blockIdx.z, x0 = blockIdx.x*64, y0 = blockIdx.y*16;
    fused_body<0>((FS*)smem, g2+(size_t)b*17952, g2+(size_t)(b+16)*17952, 136,
                  g3+(size_t)b*4896, g3+(size_t)(b+16)*4896, 72,
                  128, x0, y0, 2, b, accum);
  } else {
    int id = blockIdx.y*2 + blockIdx.x;
    tail_body(g3, accum, id, smem);
  }
}

// ================= finalize =================
__global__ __launch_bounds__(64)
void k_d6(const float* __restrict__ accum, float* __restrict__ out){
  __shared__ float s[16];
  int b = threadIdx.x;
  if (b < 16){
    float m = 0.f;
    #pragma unroll
    for (int k=0;k<7;k++){
      int hw = (512>>k)*(512>>k);
      float mean = accum[k*16+b] / (float)hw;
      m += powf(mean, 0.3f);
    }
    m *= (1.0f/7.0f);
    s[b] = powf(m, 1.6666666666666667f);
  }
  __syncthreads();
  if (b == 0){
    float t = 0.f;
    #pragma unroll
    for (int i=0;i<16;i++) t += s[i];
    out[0] = t * (1.0f/16.0f);
  }
}

extern "C" void kernel_launch(void* const* d_in, const int* in_sizes, int n_in,
                              void* d_out, int out_size, void* d_ws, size_t ws_size,
                              hipStream_t stream){
  const float* h = (const float*)d_in[0];
  const float* l = (const float*)d_in[1];
  float* out = (float*)d_out;
  float* ws = (float*)d_ws;

  float* g1 = ws;                         // 32 * 260*264
  float* g2 = g1 + 2196480;               // 32 * 132*136
  float* g3 = g2 + 574464;                // 32 * 68*72
  float* accum = g3 + 156672;             // 112

  (void)hipMemsetAsync(accum, 0, 112*sizeof(float), stream);

  size_t fsz = sizeof(FS) > sizeof(DS) ? sizeof(FS) : sizeof(DS);
  size_t tsz = sizeof(TS);

  k_d1<<<dim3(4,32,32), 256, 0, stream>>>(h, l, g1);
  k_d2<<<dim3(8,32,20), 256, fsz, stream>>>(h, l, g1, g2, accum);
  k_d4<<<dim3(4,16,20), 256, fsz, stream>>>(g1, g2, g3, accum);
  k_d5<<<dim3(2,8,17),  256, tsz, stream>>>(g2, g3, accum);
  k_d6<<<1, 64, 0, stream>>>(accum, out);
}

// Round 9
// 158.440 us; speedup vs baseline: 1.1214x; 1.1214x over previous
//
#include <hip/hip_runtime.h>

#define SIG0 0.17f
#define SIG1 4.86f

__device__ __constant__ float c_filt0[25] = {
  0.04f,0.04f,0.05f,0.04f,0.04f,
  0.04f,0.03f,0.04f,0.03f,0.04f,
  0.05f,0.04f,0.05f,0.04f,0.05f,
  0.04f,0.03f,0.04f,0.03f,0.04f,
  0.04f,0.04f,0.05f,0.04f,0.04f};
__device__ __constant__ float c_f1d[5] = {0.05f,0.25f,0.4f,0.25f,0.05f};

static __device__ __forceinline__ int iclamp(int v, int lo, int hi){
  return v < lo ? lo : (v > hi ? hi : v);
}

// Padded level buffers: level size S stored as (S+4) rows x (S+8) cols,
// logical (y,x) at [(y+2)*(S+8) + (x+4)], apron = replicate of border.
// g1: S=256 PS=264 (img stride 68640); g2: S=128 PS=136 (17952); g3: S=64 PS=72 (4896)

struct FS {                      // fused kernel: 64x16 output tile
  float sg[2][20][76];           // lap tile rows y0-2..y0+17, cols x0-4..x0+67 (72 used)
  float s1[2][12][44];           // g_{k+1} tile rows y0/2-2.., cols x0/2-4.. (40 used)
  float red[4];
};
struct DS {                      // down kernel: 64x8 output tile
  float st[20][136];
  float hs[20][64];
};
struct TS {                      // tail kernel
  float A3[2][64][66];
  float A4[2][32][34];
  float A5[2][16][18];
  float A6[2][8][10];
  float red[4];
};

// ================= down body: padded in -> padded out (out tile 64x8) =================
__device__ __forceinline__ void down_body(const float* __restrict__ in0, float* __restrict__ out0,
                                          int PSI, int PSO, int Sout, int xo0, int yo0, char* smem){
  DS* S = (DS*)smem;
  int tid = threadIdx.x;
  for (int f=tid; f<20*34; f+=256){
    int r=f/34, c4=f-34*r;
    *(float4*)&S->st[r][4*c4] = *(const float4*)&in0[(size_t)(2*yo0+r)*PSI + 2*xo0 + 4*c4];
  }
  __syncthreads();
  for (int f=tid; f<20*64; f+=256){
    int r=f>>6, xo=f&63;
    const float* rp = &S->st[r][2*xo+2];
    S->hs[r][xo] = 0.05f*rp[0]+0.25f*rp[1]+0.4f*rp[2]+0.25f*rp[3]+0.05f*rp[4];
  }
  __syncthreads();
  for (int f=tid; f<8*64; f+=256){
    int yo=f>>6, xo=f&63;
    int Y=yo0+yo, X=xo0+xo;
    float v = 0.05f*S->hs[2*yo][xo]+0.25f*S->hs[2*yo+1][xo]+0.4f*S->hs[2*yo+2][xo]
            +0.25f*S->hs[2*yo+3][xo]+0.05f*S->hs[2*yo+4][xo];
    int rlo=(Y==0)?0:(Y+2), rhi=(Y==Sout-1)?(Sout+3):(Y+2);
    int clo=(X==0)?0:(X+4), chi=(X==Sout-1)?(Sout+7):(X+4);
    for (int rr=rlo; rr<=rhi; rr++)
      for (int cc=clo; cc<=chi; cc++)
        out0[(size_t)rr*PSO+cc] = v;
  }
}

// ================= k_d1: gamma + down0 (raw input -> padded g1), out tile 64x8 =================
__global__ __launch_bounds__(256)
void k_d1(const float* __restrict__ hin, const float* __restrict__ lin,
          float* __restrict__ g1){
  __shared__ DS S;
  int xo0 = blockIdx.x*64, yo0 = blockIdx.y*8, z = blockIdx.z;
  const float* in = (z<16)? hin + (size_t)z*262144 : lin + (size_t)(z-16)*262144;
  float* out0 = g1 + (size_t)z*68640;
  int tid = threadIdx.x;
  const float e = 0.3846153846153846f;
  for (int f=tid; f<20*34; f+=256){
    int r=f/34, c4=f-34*r;
    int yy = iclamp(2*yo0-2+r, 0, 511);
    int xb = 2*xo0-4+4*c4;
    const float* rp = in + (size_t)yy*512;
    float4 v;
    if (xb>=0 && xb<=508) v = *(const float4*)&rp[xb];
    else { v.x=rp[iclamp(xb,0,511)]; v.y=rp[iclamp(xb+1,0,511)];
           v.z=rp[iclamp(xb+2,0,511)]; v.w=rp[iclamp(xb+3,0,511)]; }
    v.x=__powf(v.x,e); v.y=__powf(v.y,e); v.z=__powf(v.z,e); v.w=__powf(v.w,e);
    *(float4*)&S.st[r][4*c4] = v;
  }
  __syncthreads();
  for (int f=tid; f<20*64; f+=256){
    int r=f>>6, xo=f&63;
    const float* rp = &S.st[r][2*xo+2];
    S.hs[r][xo] = 0.05f*rp[0]+0.25f*rp[1]+0.4f*rp[2]+0.25f*rp[3]+0.05f*rp[4];
  }
  __syncthreads();
  for (int f=tid; f<8*64; f+=256){
    int yo=f>>6, xo=f&63;
    int Y=yo0+yo, X=xo0+xo;
    float v = 0.05f*S.hs[2*yo][xo]+0.25f*S.hs[2*yo+1][xo]+0.4f*S.hs[2*yo+2][xo]
            +0.25f*S.hs[2*yo+3][xo]+0.05f*S.hs[2*yo+4][xo];
    int rlo=(Y==0)?0:(Y+2), rhi=(Y==255)?259:(Y+2);
    int clo=(X==0)?0:(X+4), chi=(X==255)?263:(X+4);
    for (int rr=rlo; rr<=rhi; rr++)
      for (int cc=clo; cc<=chi; cc++)
        out0[(size_t)rr*264+cc] = v;
  }
}

// ================= fused body: lap + replicate-fix + den + diff + reduce =================
// GAMMA=1: a0/a1 are raw 512x512 inputs (apply powf); GAMMA=0: padded g_k buffers (stride PS0).
// Block partial sum -> unique out_slot (plain store; NO atomics).
template<int GAMMA>
__device__ __forceinline__ void fused_body(FS* S,
    const float* __restrict__ a0, const float* __restrict__ a1, int PS0,
    const float* __restrict__ s10, const float* __restrict__ s11, int PS1,
    int Simg, int x0, int y0, float* __restrict__ out_slot){
  int t = threadIdx.x;
  const float e = 0.3846153846153846f;

  // ---- p1a: stage sg (240 segments of 12 floats; one div) ----
  if (t < 240){
    int img = t >= 120; int t2 = img ? t-120 : t;
    int r = t2/6, q3 = t2 - 6*r;
    float w[12];
    if (GAMMA){
      int yy = iclamp(y0-2+r, 0, 511);
      int xb = x0-4+12*q3;
      const float* rp = (img ? a1 : a0) + (size_t)yy*512;
      if (xb >= 0 && xb <= 500){
        *(float4*)&w[0] = *(const float4*)&rp[xb];
        *(float4*)&w[4] = *(const float4*)&rp[xb+4];
        *(float4*)&w[8] = *(const float4*)&rp[xb+8];
      } else {
        #pragma unroll
        for (int j=0;j<12;j++) w[j] = rp[iclamp(xb+j,0,511)];
      }
      #pragma unroll
      for (int j=0;j<12;j++) w[j] = __powf(w[j], e);
    } else {
      const float* rp = (img ? a1 : a0) + (size_t)(y0+r)*PS0 + x0 + 12*q3;
      *(float4*)&w[0] = *(const float4*)&rp[0];
      *(float4*)&w[4] = *(const float4*)&rp[4];
      *(float4*)&w[8] = *(const float4*)&rp[8];
    }
    float* dp = &S->sg[img][r][12*q3];
    *(float4*)&dp[0] = *(float4*)&w[0];
    *(float4*)&dp[4] = *(float4*)&w[4];
    *(float4*)&dp[8] = *(float4*)&w[8];
  }
  // ---- p1b: stage s1 (240 f4 segments: 2 img x 12 rows x 10 f4 = 40 cols) ----
  if (t < 240){
    int img = t >= 120; int t2 = img ? t-120 : t;
    int ro = t2/10, co = t2 - 10*ro;
    const float* src = (img ? s11 : s10) + (size_t)(y0/2+ro)*PS1 + x0/2 + 4*co;
    *(float4*)&S->s1[img][ro][4*co] = *(const float4*)src;
  }
  __syncthreads();

  // ---- p2: lap in place; waves 0-1 even rows, waves 2-3 odd rows (wave-uniform branch) ----
  {
    int tt = t & 127;
    bool ew = t < 128;
    if (tt < 120){
      int img = tt >= 60; int t2 = img ? tt-60 : tt;
      int rh = t2/6, q3 = t2 - 6*rh;       // rh 0..9
      int r = ew ? 2*rh : 2*rh+1;
      int cb = 6*q3;
      float B[12], C[12], u[12];
      {
        const float* pB = &S->s1[img][rh+1][cb];
        const float* pC = &S->s1[img][rh+2][cb];
        *(float4*)&B[0]=*(const float4*)&pB[0]; *(float4*)&B[4]=*(const float4*)&pB[4]; *(float4*)&B[8]=*(const float4*)&pB[8];
        *(float4*)&C[0]=*(const float4*)&pC[0]; *(float4*)&C[4]=*(const float4*)&pC[4]; *(float4*)&C[8]=*(const float4*)&pC[8];
      }
      if (ew){
        float A[12];
        const float* pA = &S->s1[img][rh][cb];
        *(float4*)&A[0]=*(const float4*)&pA[0]; *(float4*)&A[4]=*(const float4*)&pA[4]; *(float4*)&A[8]=*(const float4*)&pA[8];
        #pragma unroll
        for (int m=0;m<6;m++){
          float hEA = 0.05f*A[m+1]+0.4f*A[m+2]+0.05f*A[m+3];
          float hEB = 0.05f*B[m+1]+0.4f*B[m+2]+0.05f*B[m+3];
          float hEC = 0.05f*C[m+1]+0.4f*C[m+2]+0.05f*C[m+3];
          u[2*m]   = 0.2f*hEA + 1.6f*hEB + 0.2f*hEC;
          float hOA = 0.25f*(A[m+2]+A[m+3]);
          float hOB = 0.25f*(B[m+2]+B[m+3]);
          float hOC = 0.25f*(C[m+2]+C[m+3]);
          u[2*m+1] = 0.2f*hOA + 1.6f*hOB + 0.2f*hOC;
        }
      } else {
        #pragma unroll
        for (int m=0;m<6;m++){
          float hEB = 0.05f*B[m+1]+0.4f*B[m+2]+0.05f*B[m+3];
          float hEC = 0.05f*C[m+1]+0.4f*C[m+2]+0.05f*C[m+3];
          u[2*m]   = hEB + hEC;
          u[2*m+1] = 0.25f*(B[m+2]+B[m+3]) + 0.25f*(C[m+2]+C[m+3]);
        }
      }
      float* dp = &S->sg[img][r][12*q3];
      float v[12];
      *(float4*)&v[0]=*(float4*)&dp[0]; *(float4*)&v[4]=*(float4*)&dp[4]; *(float4*)&v[8]=*(float4*)&dp[8];
      #pragma unroll
      for (int j=0;j<12;j++) v[j] -= u[j];
      *(float4*)&dp[0]=*(float4*)&v[0]; *(float4*)&dp[4]=*(float4*)&v[4]; *(float4*)&dp[8]=*(float4*)&v[8];
    }
  }
  __syncthreads();

  // ---- replicate fix-up on lap tile borders ----
  bool top=(y0==0), bot=(y0+16==Simg), lft=(x0==0), rgt=(x0+64==Simg);
  if (top|bot|lft|rgt){
    for (int f=t; f<2*18; f+=256){
      int img = f>=18; int q = img ? f-18 : f;
      if (top){ float4 v=*(float4*)&S->sg[img][2][4*q];
                *(float4*)&S->sg[img][0][4*q]=v; *(float4*)&S->sg[img][1][4*q]=v; }
      if (bot){ float4 v=*(float4*)&S->sg[img][17][4*q];
                *(float4*)&S->sg[img][18][4*q]=v; *(float4*)&S->sg[img][19][4*q]=v; }
    }
    __syncthreads();
    for (int f=t; f<2*20; f+=256){
      int img = f>=20; int r = img ? f-20 : f;
      if (lft){ float v=S->sg[img][r][4];  float4 vv={v,v,v,v}; *(float4*)&S->sg[img][r][0]=vv; }
      if (rgt){ float v=S->sg[img][r][67]; float4 vv={v,v,v,v}; *(float4*)&S->sg[img][r][68]=vv; }
    }
    __syncthreads();
  }

  // ---- p3: streaming den conv (box trick). Thread: 4x2 quad of ONE image (img = t&1). ----
  // den = SIG0 + 0.04*T + 0.01*s05 - 0.01*s03
  float vacc = 0.f;
  {
    int img = t & 1, quad = t >> 1;
    int qx = quad & 15, qy = quad >> 4;   // qx 0..15, qy 0..7
    int cb = 4*qx, rb = 2*qy;
    float T0[4]={0,0,0,0}, T1[4]={0,0,0,0};
    float s5a[4], s5b[4], s3a[4], s3b[4], n0[4], n1[4];
    #pragma unroll
    for (int r=0;r<6;r++){
      float w[12];
      const float* rp = &S->sg[img][rb+r][cb];
      *(float4*)&w[0]=*(const float4*)&rp[0];
      *(float4*)&w[4]=*(const float4*)&rp[4];
      *(float4*)&w[8]=*(const float4*)&rp[8];
      float aw[8];
      #pragma unroll
      for (int j=0;j<8;j++) aw[j] = fabsf(w[j+2]);
      float h0 = ((aw[0]+aw[1])+(aw[2]+aw[3]))+aw[4];
      float h1 = h0 - aw[0] + aw[5];
      float h2 = h1 - aw[1] + aw[6];
      float h3 = h2 - aw[2] + aw[7];
      float hh[4] = {h0,h1,h2,h3};
      if (r<=4){
        #pragma unroll
        for (int c=0;c<4;c++) T0[c] += hh[c];
      }
      if (r>=1){
        #pragma unroll
        for (int c=0;c<4;c++) T1[c] += hh[c];
      }
      if (r==0){
        for (int c=0;c<4;c++) s5a[c] = aw[c+2];
      }
      if (r==1){
        for (int c=0;c<4;c++){ s3a[c] = aw[c+1]+aw[c+3]; s5b[c] = aw[c+2]; }
      }
      if (r==2){
        for (int c=0;c<4;c++){ s5a[c] += aw[c]+aw[c+2]+aw[c+4]; n0[c]=w[c+4]; s3b[c] = aw[c+1]+aw[c+3]; }
      }
      if (r==3){
        for (int c=0;c<4;c++){ s3a[c] += aw[c+1]+aw[c+3]; s5b[c] += aw[c]+aw[c+2]+aw[c+4]; n1[c]=w[c+4]; }
      }
      if (r==4){
        for (int c=0;c<4;c++){ s5a[c] += aw[c+2]; s3b[c] += aw[c+1]+aw[c+3]; }
      }
      if (r==5){
        for (int c=0;c<4;c++) s5b[c] += aw[c+2];
      }
    }
    float qv[8];
    #pragma unroll
    for (int c=0;c<4;c++){
      float d0 = SIG0 + 0.04f*T0[c] + 0.01f*s5a[c] - 0.01f*s3a[c];
      float d1 = SIG0 + 0.04f*T1[c] + 0.01f*s5b[c] - 0.01f*s3b[c];
      qv[c]   = __fdividef(n0[c], d0);
      qv[4+c] = __fdividef(n1[c], d1);
    }
    #pragma unroll
    for (int i=0;i<8;i++){
      float o = __shfl_xor(qv[i], 1);
      float d = qv[i] - o;
      vacc += d*d;
    }
    if (img) vacc = 0.f;   // count each pair once
  }
  #pragma unroll
  for (int off=32; off>0; off>>=1) vacc += __shfl_down(vacc, off);
  if ((t&63)==0) S->red[t>>6] = vacc;
  __syncthreads();
  if (t==0)
    out_slot[0] = S->red[0]+S->red[1]+S->red[2]+S->red[3];
}

// ================= tail (levels 3..6) helpers =================
static __device__ __forceinline__ void down_lds(const float* Ain, int ldi, int Sin,
                                                float* Aout, int ldo, int Sout,
                                                int tid, int NT){
  int tot = 2*Sout*Sout;
  for (int f=tid; f<tot; f+=NT){
    int img = f/(Sout*Sout), rem = f%(Sout*Sout), y=rem/Sout, x=rem%Sout;
    const float* A = Ain + img*Sin*ldi;
    float s=0.f;
    #pragma unroll
    for (int i=0;i<5;i++){
      int yy=iclamp(2*y+i-2,0,Sin-1);
      float rs=0.f;
      #pragma unroll
      for (int j=0;j<5;j++){
        int xx=iclamp(2*x+j-2,0,Sin-1);
        rs += c_f1d[j]*A[yy*ldi+xx];
      }
      s += c_f1d[i]*rs;
    }
    Aout[img*Sout*ldo + y*ldo + x] = s;
  }
}

static __device__ __forceinline__ void lap_lds(float* Ak, int ldk, int S,
                                               const float* Ag, int ldg,
                                               int tid, int NT){
  int Sg = S>>1;
  int tot = 2*S*S;
  for (int f=tid; f<tot; f+=NT){
    int img=f/(S*S), rem=f%(S*S), y=rem/S, x=rem%S;
    const float* G = Ag + img*Sg*ldg;
    int y2=y>>1, x2=x>>1;
    int ry0,ry1,ry2; float wy0,wy1,wy2;
    if (!(y&1)){ ry0=iclamp(y2-1,0,Sg-1); ry1=y2; ry2=iclamp(y2+1,0,Sg-1); wy0=0.2f; wy1=1.6f; wy2=0.2f; }
    else { ry0=y2; ry1=iclamp(y2+1,0,Sg-1); ry2=y2; wy0=1.f; wy1=1.f; wy2=0.f; }
    int cx0,cx1,cx2; float wx0,wx1,wx2;
    if (!(x&1)){ cx0=iclamp(x2-1,0,Sg-1); cx1=x2; cx2=iclamp(x2+1,0,Sg-1); wx0=0.05f; wx1=0.4f; wx2=0.05f; }
    else { cx0=x2; cx1=iclamp(x2+1,0,Sg-1); cx2=x2; wx0=0.25f; wx1=0.25f; wx2=0.f; }
    float u0 = wx0*G[ry0*ldg+cx0]+wx1*G[ry0*ldg+cx1]+wx2*G[ry0*ldg+cx2];
    float u1 = wx0*G[ry1*ldg+cx0]+wx1*G[ry1*ldg+cx1]+wx2*G[ry1*ldg+cx2];
    float u2 = wx0*G[ry2*ldg+cx0]+wx1*G[ry2*ldg+cx1]+wx2*G[ry2*ldg+cx2];
    Ak[img*S*ldk + y*ldk + x] -= wy0*u0+wy1*u1+wy2*u2;
  }
}

static __device__ __forceinline__ float diff_lds(const float* A, int ld, int S,
                                                 int tid, int NT){
  float v=0.f;
  const float* Ah = A;
  const float* Al = A + S*ld;
  for (int f=tid; f<S*S; f+=NT){
    int y=f/S, x=f%S;
    float dh=SIG0, dl=SIG0;
    #pragma unroll
    for (int i=0;i<5;i++){
      int yy=iclamp(y+i-2,0,S-1);
      #pragma unroll
      for (int j=0;j<5;j++){
        int xx=iclamp(x+j-2,0,S-1);
        float w=c_filt0[i*5+j];
        dh += w*fabsf(Ah[yy*ld+xx]);
        dl += w*fabsf(Al[yy*ld+xx]);
      }
    }
    float d = __fdividef(Ah[y*ld+x],dh) - __fdividef(Al[y*ld+x],dl);
    v += d*d;
  }
  return v;
}

__device__ void tail_body(const float* __restrict__ g3, float* __restrict__ accum,
                          int b, char* smem){
  TS* T = (TS*)smem;
  int tid = threadIdx.x;
  const float* s0  = g3 + (size_t)b*4896 + 148;        // (2,4) of padded 72-stride
  const float* s1p = g3 + (size_t)(b+16)*4896 + 148;
  for (int f=tid; f<2*4096; f+=256){
    int img=f>>12, rem=f&4095, r=rem>>6, c=rem&63;
    T->A3[img][r][c] = (img? s1p : s0)[(size_t)r*72+c];
  }
  __syncthreads();
  down_lds(&T->A3[0][0][0],66,64,&T->A4[0][0][0],34,32,tid,256);
  __syncthreads();
  down_lds(&T->A4[0][0][0],34,32,&T->A5[0][0][0],18,16,tid,256);
  __syncthreads();
  down_lds(&T->A5[0][0][0],18,16,&T->A6[0][0][0],10,8,tid,256);
  __syncthreads();
  lap_lds(&T->A3[0][0][0],66,64,&T->A4[0][0][0],34,tid,256);
  __syncthreads();
  float v3 = diff_lds(&T->A3[0][0][0],66,64,tid,256);
  lap_lds(&T->A4[0][0][0],34,32,&T->A5[0][0][0],18,tid,256);
  __syncthreads();
  float v4 = diff_lds(&T->A4[0][0][0],34,32,tid,256);
  lap_lds(&T->A5[0][0][0],18,16,&T->A6[0][0][0],10,tid,256);
  __syncthreads();
  float v5 = diff_lds(&T->A5[0][0][0],18,16,tid,256);
  float v6 = 0.f;
  for (int f=tid; f<64; f+=256){
    float ch = T->A6[0][f>>3][f&7];
    float cl = T->A6[1][f>>3][f&7];
    float d = __fdividef(ch, fabsf(ch)+SIG1) - __fdividef(cl, fabsf(cl)+SIG1);
    v6 += d*d;
  }
  float vs[4] = {v3, v4, v5, v6};
  #pragma unroll
  for (int k=0;k<4;k++){
    float v = vs[k];
    #pragma unroll
    for (int off=32; off>0; off>>=1) v += __shfl_down(v, off);
    if ((tid&63)==0) T->red[tid>>6] = v;
    __syncthreads();
    if (tid==0)
      accum[(3+k)*16 + b] = T->red[0]+T->red[1]+T->red[2]+T->red[3];
    __syncthreads();
  }
}

// ================= co-launched dispatch kernels =================
__global__ __launch_bounds__(256)
void k_d2(const float* __restrict__ h, const float* __restrict__ l,
          const float* __restrict__ g1, float* __restrict__ g2,
          float* __restrict__ p0){
  extern __shared__ char smem[];
  if (blockIdx.z < 16){
    int b = blockIdx.z, x0 = blockIdx.x*64, y0 = blockIdx.y*16;
    fused_body<1>((FS*)smem, h+(size_t)b*262144, l+(size_t)b*262144, 0,
                  g1+(size_t)b*68640, g1+(size_t)(b+16)*68640, 264,
                  512, x0, y0, p0 + b*256 + blockIdx.y*8 + blockIdx.x);
  } else {
    int id = (blockIdx.z-16)*256 + blockIdx.y*8 + blockIdx.x;
    int img = id>>5, rem = id&31, xt = rem&1, yt = rem>>1;
    down_body(g1+(size_t)img*68640, g2+(size_t)img*17952, 264, 136, 128, xt*64, yt*8, smem);
  }
}

__global__ __launch_bounds__(256)
void k_d4(const float* __restrict__ g1, float* __restrict__ g2,
          float* __restrict__ g3, float* __restrict__ p1){
  extern __shared__ char smem[];
  if (blockIdx.z < 16){
    int b = blockIdx.z, x0 = blockIdx.x*64, y0 = blockIdx.y*16;
    fused_body<0>((FS*)smem, g1+(size_t)b*68640, g1+(size_t)(b+16)*68640, 264,
                  g2+(size_t)b*17952, g2+(size_t)(b+16)*17952, 136,
                  256, x0, y0, p1 + b*64 + blockIdx.y*4 + blockIdx.x);
  } else {
    int id = (blockIdx.z-16)*64 + blockIdx.y*4 + blockIdx.x;
    int img = id>>3, yt = id&7;
    down_body(g2+(size_t)img*17952, g3+(size_t)img*4896, 136, 72, 64, 0, yt*8, smem);
  }
}

__global__ __launch_bounds__(256)
void k_d5(const float* __restrict__ g2, const float* __restrict__ g3,
          float* __restrict__ p2, float* __restrict__ accum){
  extern __shared__ char smem[];
  if (blockIdx.z < 16){
    int b = blockIdx.z, x0 = blockIdx.x*64, y0 = blockIdx.y*16;
    fused_body<0>((FS*)smem, g2+(size_t)b*17952, g2+(size_t)(b+16)*17952, 136,
                  g3+(size_t)b*4896, g3+(size_t)(b+16)*4896, 72,
                  128, x0, y0, p2 + b*16 + blockIdx.y*2 + blockIdx.x);
  } else {
    int id = blockIdx.y*2 + blockIdx.x;
    tail_body(g3, accum, id, smem);
  }
}

// ================= finalize: reduce partials + formula =================
__global__ __launch_bounds__(256)
void k_d6(const float* __restrict__ p0, const float* __restrict__ p1,
          const float* __restrict__ p2, const float* __restrict__ accum,
          float* __restrict__ out){
  __shared__ float r0[16][16];
  __shared__ float r1[16][4];
  __shared__ float r2[16];
  __shared__ float fin[16];
  int t = threadIdx.x;
  {
    int b = t>>4, c = t&15;
    float s = 0.f;
    #pragma unroll
    for (int j=0;j<16;j++) s += p0[b*256 + c*16 + j];
    r0[b][c] = s;
  }
  if (t < 64){
    int b = t>>2, c = t&3;
    float s = 0.f;
    #pragma unroll
    for (int j=0;j<16;j++) s += p1[b*64 + c*16 + j];
    r1[b][c] = s;
  }
  if (t < 16){
    float s = 0.f;
    #pragma unroll
    for (int j=0;j<16;j++) s += p2[t*16 + j];
    r2[t] = s;
  }
  __syncthreads();
  if (t < 16){
    int b = t;
    float a0 = 0.f;
    #pragma unroll
    for (int c=0;c<16;c++) a0 += r0[b][c];
    float a1 = (r1[b][0]+r1[b][1])+(r1[b][2]+r1[b][3]);
    float a2 = r2[b];
    float m = powf(a0*(1.0f/262144.0f), 0.3f)
            + powf(a1*(1.0f/65536.0f), 0.3f)
            + powf(a2*(1.0f/16384.0f), 0.3f);
    #pragma unroll
    for (int k=3;k<7;k++){
      int hw = (512>>k)*(512>>k);
      m += powf(accum[k*16+b]/(float)hw, 0.3f);
    }
    m *= (1.0f/7.0f);
    fin[b] = powf(m, 1.6666666666666667f);
  }
  __syncthreads();
  if (t == 0){
    float s = 0.f;
    #pragma unroll
    for (int i=0;i<16;i++) s += fin[i];
    out[0] = s * (1.0f/16.0f);
  }
}

extern "C" void kernel_launch(void* const* d_in, const int* in_sizes, int n_in,
                              void* d_out, int out_size, void* d_ws, size_t ws_size,
                              hipStream_t stream){
  const float* h = (const float*)d_in[0];
  const float* l = (const float*)d_in[1];
  float* out = (float*)d_out;
  float* ws = (float*)d_ws;

  float* g1 = ws;                         // 32 * 260*264
  float* g2 = g1 + 2196480;               // 32 * 132*136
  float* g3 = g2 + 574464;                // 32 * 68*72
  float* accum = g3 + 156672;             // 112 (only [48..111] used, all written by tail)
  float* p0 = accum + 112;                // 4096 level-0 block partials
  float* p1 = p0 + 4096;                  // 1024 level-1 block partials
  float* p2 = p1 + 1024;                  // 256  level-2 block partials

  size_t fsz = sizeof(FS) > sizeof(DS) ? sizeof(FS) : sizeof(DS);
  size_t tsz = sizeof(TS);

  k_d1<<<dim3(4,32,32), 256, 0, stream>>>(h, l, g1);
  k_d2<<<dim3(8,32,20), 256, fsz, stream>>>(h, l, g1, g2, p0);
  k_d4<<<dim3(4,16,20), 256, fsz, stream>>>(g1, g2, g3, p1);
  k_d5<<<dim3(2,8,17),  256, tsz, stream>>>(g2, g3, p2, accum);
  k_d6<<<1, 256, 0, stream>>>(p0, p1, p2, accum, out);
}